// Round 1
// baseline (172.271 us; speedup 1.0000x reference)
//
#include <hip/hip_runtime.h>

// Retrace loss: T=8192, K=2048, gamma=0.99.
// Per column: decay = cumprod(gamma*iw); S = reverse-cumsum(td*decay);
// retrace = S / max(decay, 1e-10); loss = mean(smooth_l1(q, retrace)).
// Two-level chunked scan: K1 chunk summaries -> K2 chunk prefix/suffix ->
// K3 apply + fused smooth-L1 reduction -> K4 mean.

#define GAMMA 0.99f

constexpr int T = 8192;
constexpr int K = 2048;
constexpr int N = T - 1;                 // 8191 rows
constexpr int L = 32;                    // rows per chunk
constexpr int NCHUNK = (N + L - 1) / L;  // 256 (last chunk has 31 rows)

// ---------------------------------------------------------------- K1
// Per (chunk, column): local cumprod product P and local sum Zl = sum td*ld.
__global__ __launch_bounds__(256) void retrace_k1(
    const float* __restrict__ tsv, const float* __restrict__ tev,
    const float* __restrict__ r, const float* __restrict__ ologp,
    const float* __restrict__ tlogp,
    float* __restrict__ P, float* __restrict__ Zl, double* __restrict__ acc) {
  const int k = blockIdx.x * 256 + threadIdx.x;
  const int chunk = blockIdx.y;
  const int i0 = chunk * L;
  const int iend = min(i0 + L, N);
  float p = 1.f, zl = 0.f;
  for (int i = i0; i < iend; ++i) {
    const int base = (i + 1) * K + k;
    float lw = tlogp[base] - ologp[i + 1];
    float iw = __expf(fminf(lw, 0.f));
    float c = GAMMA * iw;
    float td = fmaf(GAMMA, fmaf(-iw, tsv[base], tev[base]), r[i * K + k]);
    p *= c;
    zl = fmaf(td, p, zl);
  }
  P[chunk * K + k] = p;
  Zl[chunk * K + k] = zl;
  if (blockIdx.x == 0 && blockIdx.y == 0 && threadIdx.x == 0) *acc = 0.0;
}

// ---------------------------------------------------------------- K2
// Per column: exclusive prefix product D0 over chunks; suffix sums Ssuf of
// global chunk z-sums (D0*Zl). 2048 threads; loads batched by 8 for ILP.
__global__ __launch_bounds__(256) void retrace_k2(
    const float* __restrict__ P, const float* __restrict__ Zl,
    float* __restrict__ D0, float* __restrict__ Ssuf) {
  const int k = blockIdx.x * 256 + threadIdx.x;
  float d = 1.f;
  for (int cb = 0; cb < NCHUNK; cb += 8) {
    float buf[8];
#pragma unroll
    for (int j = 0; j < 8; ++j) buf[j] = P[(cb + j) * K + k];
#pragma unroll
    for (int j = 0; j < 8; ++j) {
      D0[(cb + j) * K + k] = d;
      d *= buf[j];
    }
  }
  float s = 0.f;
  for (int cb = NCHUNK - 8; cb >= 0; cb -= 8) {
    float bz[8], bd[8];
#pragma unroll
    for (int j = 0; j < 8; ++j) {
      bz[j] = Zl[(cb + j) * K + k];
      bd[j] = D0[(cb + j) * K + k];
    }
#pragma unroll
    for (int j = 7; j >= 0; --j) {
      Ssuf[(cb + j) * K + k] = s;
      s = fmaf(bd[j], bz[j], s);
    }
  }
}

// ---------------------------------------------------------------- K3
// Per (chunk, column): recompute td/ld into static register arrays, walk
// backward producing retrace, fuse smooth-L1, block-reduce, atomic add.
__global__ __launch_bounds__(256) void retrace_k3(
    const float* __restrict__ sv, const float* __restrict__ tsv,
    const float* __restrict__ tev, const float* __restrict__ r,
    const float* __restrict__ ologp, const float* __restrict__ tlogp,
    const float* __restrict__ D0, const float* __restrict__ Ssuf,
    double* __restrict__ acc) {
  const int k = blockIdx.x * 256 + threadIdx.x;
  const int chunk = blockIdx.y;
  const int i0 = chunk * L;
  const int nrow = min(L, N - i0);

  float ld[L], td[L];
  float p = 1.f;
#pragma unroll
  for (int s = 0; s < L; ++s) {
    if (s < nrow) {
      const int i = i0 + s;
      const int base = (i + 1) * K + k;
      float lw = tlogp[base] - ologp[i + 1];
      float iw = __expf(fminf(lw, 0.f));
      float c = GAMMA * iw;
      p *= c;
      ld[s] = p;
      td[s] = fmaf(GAMMA, fmaf(-iw, tsv[base], tev[base]), r[i * K + k]);
    }
  }

  const float d0 = D0[chunk * K + k];
  const float ssufv = Ssuf[chunk * K + k];
  float slocal = 0.f;
  float loss = 0.f;
#pragma unroll
  for (int s = L - 1; s >= 0; --s) {
    if (s < nrow) {
      const int i = i0 + s;
      slocal = fmaf(td[s], ld[s], slocal);
      float S = fmaf(d0, slocal, ssufv);
      float decay = d0 * ld[s];
      float retrace = S / fmaxf(decay, 1e-10f);
      float dd = sv[i * K + k] - retrace;
      float ad = fabsf(dd);
      loss += (ad < 1.f) ? 0.5f * dd * dd : ad - 0.5f;
    }
  }

  // wave reduce (64 lanes), then LDS across 4 waves, one atomic per block
  for (int off = 32; off > 0; off >>= 1) loss += __shfl_down(loss, off);
  __shared__ float wsum[4];
  const int lane = threadIdx.x & 63, wid = threadIdx.x >> 6;
  if (lane == 0) wsum[wid] = loss;
  __syncthreads();
  if (threadIdx.x == 0) {
    float b = wsum[0] + wsum[1] + wsum[2] + wsum[3];
    atomicAdd(acc, (double)b);
  }
}

// ---------------------------------------------------------------- K4
__global__ void retrace_k4(const double* __restrict__ acc,
                           float* __restrict__ out) {
  out[0] = (float)(*acc * (1.0 / ((double)N * (double)K)));
}

extern "C" void kernel_launch(void* const* d_in, const int* in_sizes, int n_in,
                              void* d_out, int out_size, void* d_ws,
                              size_t ws_size, hipStream_t stream) {
  const float* sv = (const float*)d_in[0];     // state_trajectory_action_values
  const float* tsv = (const float*)d_in[1];    // target_state_trajectory_action_values
  const float* tev = (const float*)d_in[2];    // target_expected_state_values
  const float* r = (const float*)d_in[3];      // rewards
  const float* ologp = (const float*)d_in[4];  // original_log_..._probs (T,)
  const float* tlogp = (const float*)d_in[5];  // target_log_..._probs (T,K)

  float* wsf = (float*)d_ws;
  const size_t CK = (size_t)NCHUNK * K;
  float* P = wsf;
  float* Zl = wsf + CK;
  float* D0 = wsf + 2 * CK;
  float* Ssuf = wsf + 3 * CK;
  double* acc = (double*)(wsf + 4 * CK);  // 8 MiB offset, 8B-aligned

  dim3 grid1(K / 256, NCHUNK);
  retrace_k1<<<grid1, 256, 0, stream>>>(tsv, tev, r, ologp, tlogp, P, Zl, acc);
  retrace_k2<<<K / 256, 256, 0, stream>>>(P, Zl, D0, Ssuf);
  retrace_k3<<<grid1, 256, 0, stream>>>(sv, tsv, tev, r, ologp, tlogp, D0,
                                        Ssuf, acc);
  retrace_k4<<<1, 1, 0, stream>>>(acc, (float*)d_out);
}